// Round 6
// baseline (189.439 us; speedup 1.0000x reference)
//
#include <hip/hip_runtime.h>
#include <cstdint>

#define DIMD 1024
#define NROWS 8192
#define KDIM 2048   // 2*DIM

typedef unsigned short u16;
typedef __bf16 bf16x8 __attribute__((ext_vector_type(8)));
typedef float f32x4 __attribute__((ext_vector_type(4)));

__device__ __forceinline__ u16 f2bf(float f) {
  unsigned u = __builtin_bit_cast(unsigned, f);
  return (u16)((u + 0x7FFFu + ((u >> 16) & 1u)) >> 16);  // RNE
}

// Branch-free exact-enough GELU (A&S 7.1.26 erf, |err| <= 1.5e-7).
__device__ __forceinline__ float gelu_exact(float x) {
  float s = 0.70710678118654752f * x;
  float a = fabsf(s);
  float k = __fdividef(1.0f, fmaf(0.3275911f, a, 1.0f));
  float p = 1.061405429f;
  p = fmaf(p, k, -1.453152027f);
  p = fmaf(p, k, 1.421413741f);
  p = fmaf(p, k, -0.284496736f);
  p = fmaf(p, k, 0.254829592f);
  p = p * k;
  float e = __expf(-s * s);
  float erf_s = copysignf(fmaf(-p, e, 1.0f), s);
  return 0.5f * x * (1.0f + erf_s);
}

// ---------------------------------------------------------------------------
// pre_kernel v2 (unchanged): conv(3x5)+bias+gelu -> x2 bf16, w2 cast.
// ---------------------------------------------------------------------------
__global__ __launch_bounds__(256) void pre_kernel(
    const float* __restrict__ ifeats, const float* __restrict__ tn,
    const float* __restrict__ ta, const float* __restrict__ cw,
    const float* __restrict__ cb, const float* __restrict__ w2,
    u16* __restrict__ x2, u16* __restrict__ w2b) {
  const int b = blockIdx.x;
  const int t = threadIdx.x;
  if (b < 1024) {                  // 8 rows per block
    const int c = t >> 7;          // out channel 0/1
    const int w0 = (t & 127) << 3; // 8 outputs starting here
    float cwn[5], cwa[5], cwi[5];
#pragma unroll
    for (int k = 0; k < 5; ++k) {
      cwn[k] = cw[c * 15 + k];
      cwa[k] = cw[c * 15 + 5 + k];
      cwi[k] = cw[c * 15 + 10 + k];
    }
    const float bias = cb[c];
    float base[8];
    {
      float wn[12], wa[12];
#pragma unroll
      for (int j = 0; j < 12; ++j) {
        int wp = w0 - 2 + j;
        bool ok = (wp >= 0) && (wp < DIMD);
        wn[j] = ok ? tn[ok ? wp : 0] : 0.f;
        wa[j] = ok ? ta[ok ? wp : 0] : 0.f;
      }
#pragma unroll
      for (int s = 0; s < 8; ++s) {
        float x = bias;
#pragma unroll
        for (int k = 0; k < 5; ++k) {
          x = fmaf(cwn[k], wn[s + k], x);
          x = fmaf(cwa[k], wa[s + k], x);
        }
        base[s] = x;
      }
    }
    const bool has_l = (w0 > 0);
    const bool has_r = (w0 < DIMD - 8);
#pragma unroll 1
    for (int r = 0; r < 8; ++r) {
      const int row = b * 8 + r;
      const float* irow = ifeats + (size_t)row * DIMD;
      float wi[12];
      float4 m0 = *(const float4*)(irow + w0);
      float4 m1 = *(const float4*)(irow + w0 + 4);
      wi[0] = has_l ? irow[w0 - 2] : 0.f;
      wi[1] = has_l ? irow[w0 - 1] : 0.f;
      wi[2] = m0.x; wi[3] = m0.y; wi[4] = m0.z; wi[5] = m0.w;
      wi[6] = m1.x; wi[7] = m1.y; wi[8] = m1.z; wi[9] = m1.w;
      wi[10] = has_r ? irow[w0 + 8] : 0.f;
      wi[11] = has_r ? irow[w0 + 9] : 0.f;
      union { u16 o[8]; uint4 u; } pk;
#pragma unroll
      for (int s = 0; s < 8; ++s) {
        float x = base[s];
#pragma unroll
        for (int k = 0; k < 5; ++k) x = fmaf(cwi[k], wi[s + k], x);
        pk.o[s] = f2bf(gelu_exact(x));
      }
      *(uint4*)(x2 + (size_t)row * KDIM + c * DIMD + w0) = pk.u;
    }
  } else {
    const int t2 = (b - 1024) * 256 + t;
    const float4* p = (const float4*)(w2 + (size_t)t2 * 8);
    float4 a = p[0], bb = p[1];
    union { u16 o[8]; uint4 v; } pk;
    pk.o[0] = f2bf(a.x);  pk.o[1] = f2bf(a.y);  pk.o[2] = f2bf(a.z);  pk.o[3] = f2bf(a.w);
    pk.o[4] = f2bf(bb.x); pk.o[5] = f2bf(bb.y); pk.o[6] = f2bf(bb.z); pk.o[7] = f2bf(bb.w);
    *(uint4*)(w2b + (size_t)t2 * 8) = pk.v;
  }
}

// ---------------------------------------------------------------------------
// GEMM v7: B direct-from-L2 into registers; A via LDS.
//   Theory: r0 and r5 both hit ~47us / MfmaUtil 26% with different schedules
//   -> shared-resource wall = LDS pipe (frag A+B = 128 KB/CU/tile ~ 20.5us
//   vs MFMA floor 16.6us). B is 4 MB = L2-resident and read by every block:
//   load B-frags straight from global (16-lane x 16B = 64B segments, L2-hit),
//   register-double-buffered one K-tile ahead. A stays via global_load_lds
//   (A panels don't fit L2; LDS gives the reuse). LDS frag traffic halves to
//   64 KB/CU/tile (~770 cyc << MFMA 1240 cyc/tile); B moves to the idle L2
//   path (~25 TB/s < 34.5 ceiling).
//   BM=BN=128, 256 thr / 4 waves, per-wave 64x64 (4x4 acc), grid 512 =
//   2 blocks/CU (cross-block overlap), BK=64, A double-buffered (32 KB LDS).
//   Pipeline per K-tile: {ds_read A-frags(t) | issue A(t+1)->LDS, B(t+1)->regs
//   -> 32 MFMA (compiler waits B(t) regs) -> vmcnt(8) drains A(t+1), keeps
//   B(t+1) in flight -> s_barrier}. In-order vmcnt: A(t+1) issued before
//   B(t+1), so one counted wait covers both streams.
//   XOR chunk swizzle for A kept verbatim (0 conflicts r0-r5).
// ---------------------------------------------------------------------------
__device__ __forceinline__ void gl_lds16(const u16* g, u16* l) {
  __builtin_amdgcn_global_load_lds(
      (__attribute__((address_space(1))) void*)g,
      (__attribute__((address_space(3))) void*)l, 16, 0, 0);
}

#define BK 64       // u16 per row per K-tile
#define NTILE 32    // KDIM / BK

// One pipelined K-tile. BUFC/BUFN: LDS A buffers (compile-time names).
// CUR/NXT: register B-frag sets (compile-time names).
#define GITER(T, BUFC, BUFN, CUR, NXT)                                         \
  {                                                                            \
    bf16x8 av[4][2];                                                           \
    _Pragma("unroll") for (int mt = 0; mt < 4; ++mt)                           \
      _Pragma("unroll") for (int ks = 0; ks < 2; ++ks)                         \
        av[mt][ks] = *(const bf16x8*)&BUFC[(wm + mt * 16 + r16) * BK +         \
                                           (((ks * 4 + quad) ^ sw) << 3)];     \
    _Pragma("unroll") for (int nt = 0; nt < 4; ++nt) pB[nt] += BK;             \
    if ((T) + 1 < NTILE) {                                                     \
      _Pragma("unroll") for (int u = 0; u < 4; ++u)                            \
        gl_lds16(gA[u] + ((T) + 1) * BK, BUFN + (wv * 32 + u * 8) * BK);       \
      _Pragma("unroll") for (int nt = 0; nt < 4; ++nt)                         \
        _Pragma("unroll") for (int ks = 0; ks < 2; ++ks)                       \
          NXT[nt][ks] = *(const bf16x8*)(pB[nt] + ks * 32);                    \
    }                                                                          \
    __builtin_amdgcn_s_setprio(1);                                             \
    _Pragma("unroll") for (int ks = 0; ks < 2; ++ks)                           \
      _Pragma("unroll") for (int mt = 0; mt < 4; ++mt)                         \
        _Pragma("unroll") for (int nt = 0; nt < 4; ++nt)                       \
          acc[mt][nt] = __builtin_amdgcn_mfma_f32_16x16x32_bf16(               \
              av[mt][ks], CUR[nt][ks], acc[mt][nt], 0, 0, 0);                  \
    __builtin_amdgcn_s_setprio(0);                                             \
    asm volatile("s_waitcnt vmcnt(8)" ::: "memory");                           \
    __builtin_amdgcn_s_barrier();                                              \
    __builtin_amdgcn_sched_barrier(0);                                         \
  }

__global__ __launch_bounds__(256, 2) void gemm_bt(
    const u16* __restrict__ A,      // x2 bf16 [8192, 2048]
    const u16* __restrict__ B,      // w2 bf16 [1024, 2048]
    const float* __restrict__ ifeats,
    const float* __restrict__ b2,
    float* __restrict__ out) {
  constexpr int K = KDIM;
  __shared__ __align__(16) u16 sA0[128 * BK];  // 16 KB
  __shared__ __align__(16) u16 sA1[128 * BK];  // 16 KB; 32 KB total

  const int tid = threadIdx.x;
  const int wv = tid >> 6;         // wave 0..3
  const int lane = tid & 63;
  // XCD swizzle: 512 blocks; xcd = id&7 owns 8 M-strips x 8 N-blocks.
  const int id = blockIdx.x;       // 0..511
  const int xcd = id & 7;
  const int s_ = id >> 3;          // 0..63
  const int i0 = (xcd * 8 + (s_ >> 3)) * 128;
  const int j0 = (s_ & 7) * 128;

  const int wm = (wv & 1) * 64;    // wave tile: 64 (M) x 64 (N)
  const int wn = (wv >> 1) * 64;
  const int quad = lane >> 4;
  const int r16 = lane & 15;
  const int sw = r16 & 7;

  // A staging: per wave 32 rows/tile, unit = 8 rows x 128 B = one gl_lds16.
  const int srow = lane >> 3;                 // 0..7
  const int schunk = (lane & 7) ^ srow;       // XOR-swizzled 16B chunk
  const u16* gA[4];
#pragma unroll
  for (int u = 0; u < 4; ++u)
    gA[u] = A + (size_t)(i0 + wv * 32 + u * 8 + srow) * K + schunk * 8;

  // B frag pointers: lane (r16, quad) reads row j0+wn+nt*16+r16, 16B at
  // col quad*8 (+ks*32). Bumped by BK per K-tile.
  const u16* pB[4];
#pragma unroll
  for (int nt = 0; nt < 4; ++nt)
    pB[nt] = B + (size_t)(j0 + wn + nt * 16 + r16) * K + quad * 8;

  const f32x4 vzero = {0.f, 0.f, 0.f, 0.f};
  f32x4 acc[4][4];
#pragma unroll
  for (int a = 0; a < 4; ++a)
#pragma unroll
    for (int b = 0; b < 4; ++b) acc[a][b] = vzero;

  bf16x8 bvX[4][2], bvY[4][2];

  // Prologue: A(0) -> sA0 (4 loads), B(0) -> bvX (8 loads).
#pragma unroll
  for (int u = 0; u < 4; ++u)
    gl_lds16(gA[u], sA0 + (wv * 32 + u * 8) * BK);
#pragma unroll
  for (int nt = 0; nt < 4; ++nt)
#pragma unroll
    for (int ks = 0; ks < 2; ++ks)
      bvX[nt][ks] = *(const bf16x8*)(pB[nt] + ks * 32);
  asm volatile("s_waitcnt vmcnt(8)" ::: "memory");   // drain A(0), keep B(0)
  __builtin_amdgcn_s_barrier();
  __builtin_amdgcn_sched_barrier(0);

  for (int t = 0; t < NTILE; t += 2) {
    GITER(t,     sA0, sA1, bvX, bvY);
    GITER(t + 1, sA1, sA0, bvY, bvX);
  }

  // epilogue: C/D layout col=lane&15, row=quad*4+reg
#pragma unroll
  for (int nt = 0; nt < 4; ++nt) {
    int col = j0 + wn + nt * 16 + r16;
    float bias = b2[col];
#pragma unroll
    for (int mt = 0; mt < 4; ++mt) {
      int rbase = i0 + wm + mt * 16 + quad * 4;
#pragma unroll
      for (int r = 0; r < 4; ++r) {
        size_t idx = (size_t)(rbase + r) * DIMD + col;
        out[idx] = ifeats[idx] + bias + acc[mt][nt][r];
      }
    }
  }
}

// ---------------------------------------------------------------------------
extern "C" void kernel_launch(void* const* d_in, const int* in_sizes, int n_in,
                              void* d_out, int out_size, void* d_ws, size_t ws_size,
                              hipStream_t stream) {
  const float* ifeats = (const float*)d_in[0];
  const float* tn     = (const float*)d_in[1];
  const float* ta     = (const float*)d_in[2];
  const float* cw     = (const float*)d_in[3];
  const float* cb     = (const float*)d_in[4];
  const float* w2     = (const float*)d_in[5];
  const float* b2     = (const float*)d_in[6];
  float* out = (float*)d_out;

  // ws: [0, 4MB) w2 bf16 | [4MB, 36MB) x2 bf16
  u16* w2b = (u16*)d_ws;
  u16* x2  = (u16*)((char*)d_ws + (size_t)DIMD * KDIM * 2);

  pre_kernel<<<2048, 256, 0, stream>>>(ifeats, tn, ta, cw, cb, w2, x2, w2b);
  gemm_bt<<<512, 256, 0, stream>>>(x2, w2b, ifeats, b2, out);
}

// Round 7
// 153.908 us; speedup vs baseline: 1.2309x; 1.2309x over previous
//
#include <hip/hip_runtime.h>
#include <cstdint>

#define DIMD 1024
#define NROWS 8192
#define KDIM 2048   // 2*DIM

typedef unsigned short u16;
typedef __bf16 bf16x8 __attribute__((ext_vector_type(8)));
typedef float f32x4 __attribute__((ext_vector_type(4)));

__device__ __forceinline__ u16 f2bf(float f) {
  unsigned u = __builtin_bit_cast(unsigned, f);
  return (u16)((u + 0x7FFFu + ((u >> 16) & 1u)) >> 16);  // RNE
}

// Branch-free exact-enough GELU (A&S 7.1.26 erf, |err| <= 1.5e-7).
__device__ __forceinline__ float gelu_exact(float x) {
  float s = 0.70710678118654752f * x;
  float a = fabsf(s);
  float k = __fdividef(1.0f, fmaf(0.3275911f, a, 1.0f));
  float p = 1.061405429f;
  p = fmaf(p, k, -1.453152027f);
  p = fmaf(p, k, 1.421413741f);
  p = fmaf(p, k, -0.284496736f);
  p = fmaf(p, k, 0.254829592f);
  p = p * k;
  float e = __expf(-s * s);
  float erf_s = copysignf(fmaf(-p, e, 1.0f), s);
  return 0.5f * x * (1.0f + erf_s);
}

// ---------------------------------------------------------------------------
// pre_kernel v2 (unchanged): conv(3x5)+bias+gelu -> x2 bf16, w2 cast.
// ---------------------------------------------------------------------------
__global__ __launch_bounds__(256) void pre_kernel(
    const float* __restrict__ ifeats, const float* __restrict__ tn,
    const float* __restrict__ ta, const float* __restrict__ cw,
    const float* __restrict__ cb, const float* __restrict__ w2,
    u16* __restrict__ x2, u16* __restrict__ w2b) {
  const int b = blockIdx.x;
  const int t = threadIdx.x;
  if (b < 1024) {                  // 8 rows per block
    const int c = t >> 7;          // out channel 0/1
    const int w0 = (t & 127) << 3; // 8 outputs starting here
    float cwn[5], cwa[5], cwi[5];
#pragma unroll
    for (int k = 0; k < 5; ++k) {
      cwn[k] = cw[c * 15 + k];
      cwa[k] = cw[c * 15 + 5 + k];
      cwi[k] = cw[c * 15 + 10 + k];
    }
    const float bias = cb[c];
    float base[8];
    {
      float wn[12], wa[12];
#pragma unroll
      for (int j = 0; j < 12; ++j) {
        int wp = w0 - 2 + j;
        bool ok = (wp >= 0) && (wp < DIMD);
        wn[j] = ok ? tn[ok ? wp : 0] : 0.f;
        wa[j] = ok ? ta[ok ? wp : 0] : 0.f;
      }
#pragma unroll
      for (int s = 0; s < 8; ++s) {
        float x = bias;
#pragma unroll
        for (int k = 0; k < 5; ++k) {
          x = fmaf(cwn[k], wn[s + k], x);
          x = fmaf(cwa[k], wa[s + k], x);
        }
        base[s] = x;
      }
    }
    const bool has_l = (w0 > 0);
    const bool has_r = (w0 < DIMD - 8);
#pragma unroll 1
    for (int r = 0; r < 8; ++r) {
      const int row = b * 8 + r;
      const float* irow = ifeats + (size_t)row * DIMD;
      float wi[12];
      float4 m0 = *(const float4*)(irow + w0);
      float4 m1 = *(const float4*)(irow + w0 + 4);
      wi[0] = has_l ? irow[w0 - 2] : 0.f;
      wi[1] = has_l ? irow[w0 - 1] : 0.f;
      wi[2] = m0.x; wi[3] = m0.y; wi[4] = m0.z; wi[5] = m0.w;
      wi[6] = m1.x; wi[7] = m1.y; wi[8] = m1.z; wi[9] = m1.w;
      wi[10] = has_r ? irow[w0 + 8] : 0.f;
      wi[11] = has_r ? irow[w0 + 9] : 0.f;
      union { u16 o[8]; uint4 u; } pk;
#pragma unroll
      for (int s = 0; s < 8; ++s) {
        float x = base[s];
#pragma unroll
        for (int k = 0; k < 5; ++k) x = fmaf(cwi[k], wi[s + k], x);
        pk.o[s] = f2bf(gelu_exact(x));
      }
      *(uint4*)(x2 + (size_t)row * KDIM + c * DIMD + w0) = pk.u;
    }
  } else {
    const int t2 = (b - 1024) * 256 + t;
    const float4* p = (const float4*)(w2 + (size_t)t2 * 8);
    float4 a = p[0], bb = p[1];
    union { u16 o[8]; uint4 v; } pk;
    pk.o[0] = f2bf(a.x);  pk.o[1] = f2bf(a.y);  pk.o[2] = f2bf(a.z);  pk.o[3] = f2bf(a.w);
    pk.o[4] = f2bf(bb.x); pk.o[5] = f2bf(bb.y); pk.o[6] = f2bf(bb.z); pk.o[7] = f2bf(bb.w);
    *(uint4*)(w2b + (size_t)t2 * 8) = pk.v;
  }
}

// ---------------------------------------------------------------------------
// GEMM v8: r5 skeleton + register frag double-buffer = LDS/MFMA pipe overlap.
//   Diagnosis (r5 counters): per-CU per-K-tile measured 3525 cyc vs LDS-pipe
//   1920 (1536 frag ds_read_b128 + 384 stage-writes) and MFMA 1240 -- the
//   barrier lockstep serialized {ds_read phase}->{MFMA phase}. Fix: read
//   frags(t+1) into a second register set BEFORE MFMA(t); one barrier/tile.
//   The inter-barrier window then holds both pipes' work, wave-skewed ->
//   per-tile ~max(1920,1240)+eps instead of the sum.
//   Flight schedule (re-derived): frag-read one tile ahead consumes one tile
//   of lead, so prefetch depth 3: gl_lds(t+3)->buf[t%3] (freed at t-1's
//   lgkm(0)+barrier); frags(t+1)<-buf[(t+1)%3] (resident via vmcnt(6) at end
//   of t-1); end-of-t vmcnt(6) drains t+2, keeps t+3 (~4500 cyc slack).
//   BM=256,BN=128,BK=64, 8 waves, per-wave 64x64 (4x4), grid 256 = 1/CU.
//   3 bufs = 144 KB LDS. XOR chunk swizzle verbatim (0 conflicts r0-r5).
//   B back in LDS (r6: B-from-L2 put VMEM latency on the critical path).
// ---------------------------------------------------------------------------
__device__ __forceinline__ void gl_lds16(const u16* g, u16* l) {
  __builtin_amdgcn_global_load_lds(
      (__attribute__((address_space(1))) void*)g,
      (__attribute__((address_space(3))) void*)l, 16, 0, 0);
}

#define BK 64       // u16 per row per K-tile
#define BM 256
#define BN 128
#define NTILE 32    // KDIM / BK

// One K-tile. AVC/BVC: frag set for MFMA(t). AVN/BVN: set filled for t+1.
#define GITER(T, AVC, BVC, AVN, BVN)                                           \
  {                                                                            \
    if ((T) + 1 < NTILE) {                                                     \
      _Pragma("unroll") for (int mt = 0; mt < 4; ++mt)                         \
        _Pragma("unroll") for (int ks = 0; ks < 2; ++ks)                       \
          AVN[mt][ks] = *(const bf16x8*)&pa1[(wm + mt * 16 + r16) * BK +       \
                                             (((ks * 4 + quad) ^ sw) << 3)];   \
      _Pragma("unroll") for (int nt = 0; nt < 4; ++nt)                         \
        _Pragma("unroll") for (int ks = 0; ks < 2; ++ks)                       \
          BVN[nt][ks] = *(const bf16x8*)&pb1[(wn + nt * 16 + r16) * BK +       \
                                             (((ks * 4 + quad) ^ sw) << 3)];   \
    }                                                                          \
    if ((T) + 3 < NTILE) {                                                     \
      _Pragma("unroll") for (int u = 0; u < 4; ++u)                            \
        gl_lds16(gA[u] + ((T) + 3) * BK, pa0 + (wv * 32 + u * 8) * BK);        \
      _Pragma("unroll") for (int u = 0; u < 2; ++u)                            \
        gl_lds16(gB[u] + ((T) + 3) * BK, pb0 + (wv * 16 + u * 8) * BK);        \
    }                                                                          \
    __builtin_amdgcn_sched_barrier(0);                                         \
    __builtin_amdgcn_s_setprio(1);                                             \
    _Pragma("unroll") for (int ks = 0; ks < 2; ++ks)                           \
      _Pragma("unroll") for (int mt = 0; mt < 4; ++mt)                         \
        _Pragma("unroll") for (int nt = 0; nt < 4; ++nt)                       \
          acc[mt][nt] = __builtin_amdgcn_mfma_f32_16x16x32_bf16(               \
              AVC[mt][ks], BVC[nt][ks], acc[mt][nt], 0, 0, 0);                 \
    __builtin_amdgcn_s_setprio(0);                                             \
    if ((T) + 3 < NTILE) asm volatile("s_waitcnt vmcnt(6)" ::: "memory");      \
    else                 asm volatile("s_waitcnt vmcnt(0)" ::: "memory");      \
    asm volatile("s_waitcnt lgkmcnt(0)" ::: "memory");                         \
    __builtin_amdgcn_s_barrier();                                              \
    __builtin_amdgcn_sched_barrier(0);                                         \
    u16* x_;                                                                   \
    x_ = pa0; pa0 = pa1; pa1 = pa2; pa2 = x_;                                  \
    x_ = pb0; pb0 = pb1; pb1 = pb2; pb2 = x_;                                  \
  }

__global__ __launch_bounds__(512, 1) void gemm_bt(
    const u16* __restrict__ A,      // x2 bf16 [8192, 2048]
    const u16* __restrict__ B,      // w2 bf16 [1024, 2048]
    const float* __restrict__ ifeats,
    const float* __restrict__ b2,
    float* __restrict__ out) {
  constexpr int K = KDIM;
  __shared__ __align__(16) u16 sA[3][BM * BK];  // 3 x 32 KB
  __shared__ __align__(16) u16 sB[3][BN * BK];  // 3 x 16 KB; 144 KB total

  const int tid = threadIdx.x;
  const int wv = tid >> 6;         // wave 0..7
  const int lane = tid & 63;
  // XCD swizzle: 256 blocks; xcd = id&7 owns 4 M-strips x 8 N-blocks.
  const int id = blockIdx.x;       // 0..255
  const int xcd = id & 7;
  const int s_ = id >> 3;          // 0..31
  const int i0 = (xcd * 4 + (s_ >> 3)) * BM;
  const int j0 = (s_ & 7) * BN;

  const int wm = (wv >> 1) * 64;   // wave tile 64x64; 4M x 2N wave grid
  const int wn = (wv & 1) * 64;
  const int quad = lane >> 4;
  const int r16 = lane & 15;
  const int sw = r16 & 7;

  // staging: unit = 8 rows x 128 B = one gl_lds16. A 4 units/wave, B 2.
  const int srow = lane >> 3;                 // 0..7
  const int schunk = (lane & 7) ^ srow;       // XOR-swizzled 16B chunk
  const u16* gA[4];
  const u16* gB[2];
#pragma unroll
  for (int u = 0; u < 4; ++u)
    gA[u] = A + (size_t)(i0 + wv * 32 + u * 8 + srow) * K + schunk * 8;
#pragma unroll
  for (int u = 0; u < 2; ++u)
    gB[u] = B + (size_t)(j0 + wv * 16 + u * 8 + srow) * K + schunk * 8;

  const f32x4 vzero = {0.f, 0.f, 0.f, 0.f};
  f32x4 acc[4][4];
#pragma unroll
  for (int a = 0; a < 4; ++a)
#pragma unroll
    for (int b = 0; b < 4; ++b) acc[a][b] = vzero;

  u16* pa0 = (u16*)sA[0]; u16* pa1 = (u16*)sA[1]; u16* pa2 = (u16*)sA[2];
  u16* pb0 = (u16*)sB[0]; u16* pb1 = (u16*)sB[1]; u16* pb2 = (u16*)sB[2];

  bf16x8 avX[4][2], bvX[4][2], avY[4][2], bvY[4][2];

  // Prologue: tiles 0,1,2 -> bufs 0,1,2 (6 loads/thread each).
#pragma unroll
  for (int tt = 0; tt < 3; ++tt) {
    u16* ba = (tt == 0) ? pa0 : (tt == 1) ? pa1 : pa2;
    u16* bb = (tt == 0) ? pb0 : (tt == 1) ? pb1 : pb2;
#pragma unroll
    for (int u = 0; u < 4; ++u)
      gl_lds16(gA[u] + tt * BK, ba + (wv * 32 + u * 8) * BK);
#pragma unroll
    for (int u = 0; u < 2; ++u)
      gl_lds16(gB[u] + tt * BK, bb + (wv * 16 + u * 8) * BK);
  }
  asm volatile("s_waitcnt vmcnt(6)" ::: "memory");   // tiles 0,1 resident
  __builtin_amdgcn_s_barrier();
  // frags(0) -> X
#pragma unroll
  for (int mt = 0; mt < 4; ++mt)
#pragma unroll
    for (int ks = 0; ks < 2; ++ks)
      avX[mt][ks] = *(const bf16x8*)&pa0[(wm + mt * 16 + r16) * BK +
                                         (((ks * 4 + quad) ^ sw) << 3)];
#pragma unroll
  for (int nt = 0; nt < 4; ++nt)
#pragma unroll
    for (int ks = 0; ks < 2; ++ks)
      bvX[nt][ks] = *(const bf16x8*)&pb0[(wn + nt * 16 + r16) * BK +
                                         (((ks * 4 + quad) ^ sw) << 3)];
  asm volatile("s_waitcnt lgkmcnt(0)" ::: "memory");
  __builtin_amdgcn_s_barrier();
  __builtin_amdgcn_sched_barrier(0);

  for (int t = 0; t < NTILE; t += 2) {
    GITER(t,     avX, bvX, avY, bvY);
    GITER(t + 1, avY, bvY, avX, bvX);
  }

  // epilogue: C/D layout col=lane&15, row=quad*4+reg
#pragma unroll
  for (int nt = 0; nt < 4; ++nt) {
    int col = j0 + wn + nt * 16 + r16;
    float bias = b2[col];
#pragma unroll
    for (int mt = 0; mt < 4; ++mt) {
      int rbase = i0 + wm + mt * 16 + quad * 4;
#pragma unroll
      for (int r = 0; r < 4; ++r) {
        size_t idx = (size_t)(rbase + r) * DIMD + col;
        out[idx] = ifeats[idx] + bias + acc[mt][nt][r];
      }
    }
  }
}

// ---------------------------------------------------------------------------
extern "C" void kernel_launch(void* const* d_in, const int* in_sizes, int n_in,
                              void* d_out, int out_size, void* d_ws, size_t ws_size,
                              hipStream_t stream) {
  const float* ifeats = (const float*)d_in[0];
  const float* tn     = (const float*)d_in[1];
  const float* ta     = (const float*)d_in[2];
  const float* cw     = (const float*)d_in[3];
  const float* cb     = (const float*)d_in[4];
  const float* w2     = (const float*)d_in[5];
  const float* b2     = (const float*)d_in[6];
  float* out = (float*)d_out;

  // ws: [0, 4MB) w2 bf16 | [4MB, 36MB) x2 bf16
  u16* w2b = (u16*)d_ws;
  u16* x2  = (u16*)((char*)d_ws + (size_t)DIMD * KDIM * 2);

  pre_kernel<<<2048, 256, 0, stream>>>(ifeats, tn, ta, cw, cb, w2, x2, w2b);
  gemm_bt<<<256, 512, 0, stream>>>(x2, w2b, ifeats, b2, out);
}